// Round 12
// baseline (198.318 us; speedup 1.0000x reference)
//
#include <hip/hip_runtime.h>
#include <hip/hip_fp16.h>
#include <math.h>

#define BB 4
#define CC 128
#define HF 128
#define WF 128
#define GATHER_NB 2048   // 8 groups x 256 blocks

typedef float f4 __attribute__((ext_vector_type(4)));
typedef unsigned int u2 __attribute__((ext_vector_type(2)));

// ---------- helpers with fp-contract OFF to bit-match the numpy reference ----------
__device__ __forceinline__ float wsum3(float a, float wa, float b, float wb, float c, float wc) {
#pragma clang fp contract(off)
    {
        float r = a * wa;
        r = r + b * wb;
        r = r + c * wc;
        return r;
    }
}

__device__ __forceinline__ float to_pix(float cv, int Wm1, int WFm1) {
#pragma clang fp contract(off)
    {
        float g = cv / (float)Wm1 * 2.0f - 1.0f;
        return (g + 1.0f) * 0.5f * (float)WFm1;
    }
}

__device__ __forceinline__ unsigned short f32_bf16_rne(float f) {
    unsigned int u = __float_as_uint(f);
    unsigned int r = u + 0x7fffu + ((u >> 16) & 1u);
    return (unsigned short)(r >> 16);
}

// ---------- 1. NCHW -> NHWC bf16 transpose of feature_map, fused with depth init ----------
__global__ void transpose_fm(const float* __restrict__ fm, unsigned short* __restrict__ fmT,
                             float* __restrict__ depth) {
    __shared__ float tile[32][33];
    int b = blockIdx.z;
    int hw0 = blockIdx.x * 32;
    int c0 = blockIdx.y * 32;
    int tx = threadIdx.x;
    int ty = threadIdx.y;
    int gid = (((blockIdx.z * gridDim.y + blockIdx.y) * gridDim.x + blockIdx.x) << 8) +
              (ty << 5) + tx;
    if (gid < BB * 512 * 512) depth[gid] = INFINITY;
    const float* in = fm + (size_t)b * CC * HF * WF;
    unsigned short* out = fmT + (size_t)b * HF * WF * CC;
    #pragma unroll
    for (int i = ty; i < 32; i += 8)
        tile[i][tx] = in[(size_t)(c0 + i) * (HF * WF) + hw0 + tx];
    __syncthreads();
    #pragma unroll
    for (int i = ty; i < 32; i += 8)
        out[(size_t)(hw0 + i) * CC + c0 + tx] = f32_bf16_rne(tile[tx][i]);
}

// ---------- 2. scatter-min of vertex depths ----------
__global__ void depth_scatter(const float* __restrict__ v2d, const float* __restrict__ v3d,
                              float* __restrict__ depth, int Nv, const int* pH, const int* pW) {
    int H = *pH, W = *pW;
    int i = blockIdx.x * blockDim.x + threadIdx.x;
    if (i >= BB * Nv) return;
    int b = i / Nv, v = i - b * Nv;
    float x = v2d[((size_t)b * Nv + v) * 2 + 0];
    float y = v2d[((size_t)b * Nv + v) * 2 + 1];
    int xv = (int)rintf(x);
    int yv = (int)rintf(y);
    if (xv < 0 || xv >= W || yv < 0 || yv >= H) return;
    float z = v3d[((size_t)b * Nv + v) * 3 + 2];
    atomicMin((int*)&depth[(size_t)b * H * W + (size_t)yv * W + xv], __float_as_int(z));
}

// ---------- 3. fused setup + gather; groups = (batch, point-half) ----------
// All non-slab reads are NONTEMPORAL (no L2 allocate) and vw/c3 leave through
// LDS-staged vectorized NT stores, so the per-XCD L2 holds ONLY the 4 MiB slab.
__global__ void __launch_bounds__(256)
gather_fused(const unsigned short* __restrict__ fmT,
             const float* __restrict__ v2d, const float* __restrict__ v3d,
             const int* __restrict__ parents, const float* __restrict__ bary,
             const float* __restrict__ depth,
             float* __restrict__ out_vw, float* __restrict__ out_c3,
             float* __restrict__ out, int N, int Nv, int K,
             const int* pH, const int* pW) {
    __shared__ u2 sp[256];
    __shared__ float svw[256];
    __shared__ float sc3f[768];
    int tid = threadIdx.x;
    int group = blockIdx.x & 7;       // -> XCD
    int off = blockIdx.x >> 3;        // 0..255 within group
    int b = group >> 1;               // batch
    int p = group & 1;                // point half
    int half = (N + 1) >> 1;
    int gstart = p * half;
    int gend = min(gstart + half, N);
    int span = (((gend - gstart + 255) >> 8) * 256 + 255) / 256;   // points/block
    span = ((gend - gstart + 255) / 256 + 255) / 256;              // (unused scratch)
    span = ((gend - gstart + 255) >> 8);                           // ceil/256 blocks? no:
    // span = points per block, padded to multiple of 8 for f4-aligned tiles
    span = (gend - gstart + GATHER_NB / 8 - 1) / (GATHER_NB / 8);
    span = (span + 7) & ~7;
    int start = gstart + off * span;
    int end = min(start + span, gend);
    int H = *pH, W = *pW;
    int lane = tid & 31;              // 32 lanes x 4 ch = 128 channels
    int slot = tid >> 5;              // 8 point-slots
    int co = lane * 4;
    const unsigned short* base = fmT + (size_t)b * HF * WF * CC;
    const float* v2b = v2d + (size_t)b * Nv * 2;
    const float* v3b = v3d + (size_t)b * Nv * 3;
    const float* dep = depth + (size_t)b * H * W;
    f4* obase = (f4*)out + (size_t)b * N * (CC / 4);

    for (int t0 = start; t0 < end; t0 += 256) {
        int cnt = min(end - t0, 256);
        // ---- phase 1: setup for up to 256 points (all non-slab reads NT) ----
        if (tid < cnt) {
            int n = t0 + tid;
            int k = n % K;
            float w0 = bary[k * 3 + 0], w1 = bary[k * 3 + 1], w2 = bary[k * 3 + 2];
            int i0 = __builtin_nontemporal_load(&parents[(size_t)n * 3 + 0]);
            int i1 = __builtin_nontemporal_load(&parents[(size_t)n * 3 + 1]);
            int i2 = __builtin_nontemporal_load(&parents[(size_t)n * 3 + 2]);
            float ax = __builtin_nontemporal_load(&v2b[(size_t)i0 * 2]);
            float ay = __builtin_nontemporal_load(&v2b[(size_t)i0 * 2 + 1]);
            float bx = __builtin_nontemporal_load(&v2b[(size_t)i1 * 2]);
            float by = __builtin_nontemporal_load(&v2b[(size_t)i1 * 2 + 1]);
            float cx = __builtin_nontemporal_load(&v2b[(size_t)i2 * 2]);
            float cy = __builtin_nontemporal_load(&v2b[(size_t)i2 * 2 + 1]);
            float c2x = wsum3(ax, w0, bx, w1, cx, w2);
            float c2y = wsum3(ay, w0, by, w1, cy, w2);
            float a0 = __builtin_nontemporal_load(&v3b[(size_t)i0 * 3]);
            float a1 = __builtin_nontemporal_load(&v3b[(size_t)i0 * 3 + 1]);
            float a2 = __builtin_nontemporal_load(&v3b[(size_t)i0 * 3 + 2]);
            float b0 = __builtin_nontemporal_load(&v3b[(size_t)i1 * 3]);
            float b1 = __builtin_nontemporal_load(&v3b[(size_t)i1 * 3 + 1]);
            float b2 = __builtin_nontemporal_load(&v3b[(size_t)i1 * 3 + 2]);
            float c0 = __builtin_nontemporal_load(&v3b[(size_t)i2 * 3]);
            float c1 = __builtin_nontemporal_load(&v3b[(size_t)i2 * 3 + 1]);
            float c2 = __builtin_nontemporal_load(&v3b[(size_t)i2 * 3 + 2]);
            float c3x = wsum3(a0, w0, b0, w1, c0, w2);
            float c3y = wsum3(a1, w0, b1, w1, c1, w2);
            float c3z = wsum3(a2, w0, b2, w1, c2, w2);
            float e1x = b0 - a0, e1y = b1 - a1, e1z = b2 - a2;
            float e2x = c0 - a0, e2y = c1 - a1, e2z = c2 - a2;
            float nx = e1y * e2z - e1z * e2y;
            float ny = e1z * e2x - e1x * e2z;
            float nz = e1x * e2y - e1y * e2x;
            float nn = sqrtf(nx * nx + ny * ny + nz * nz) + 1e-8f;
            nx /= nn; ny /= nn; nz /= nn;
            float vn = sqrtf(c3x * c3x + c3y * c3y + c3z * c3z) + 1e-8f;
            float vx = -c3x / vn, vy = -c3y / vn, vz = -c3z / vn;
            float ang = fmaxf(nx * vx + ny * vy + nz * vz, 0.0f);
            int xc = (int)rintf(c2x); xc = min(max(xc, 0), W - 1);
            int yc = (int)rintf(c2y); yc = min(max(yc, 0), H - 1);
            float dsamp = __builtin_nontemporal_load(&dep[(size_t)yc * W + xc]);
            bool visible = (c3z <= dsamp + 1e-3f) || isinf(dsamp);
            svw[tid] = visible ? ang : 0.0f;
            sc3f[tid * 3 + 0] = c3x;
            sc3f[tid * 3 + 1] = c3y;
            sc3f[tid * 3 + 2] = c3z;
            float px = to_pix(c2x, W - 1, WF - 1);
            float py = to_pix(c2y, H - 1, HF - 1);
            float x0f = floorf(px), y0f = floorf(py);
            int x0i = (int)x0f, y0i = (int)y0f;
            float wx = px - x0f, wy = py - y0f;
            unsigned int xs = (unsigned int)min(max(x0i + 8, 0), 65535);
            unsigned int ys = (unsigned int)min(max(y0i + 8, 0), 65535);
            unsigned short hx = __half_as_ushort(__float2half(wx));
            unsigned short hy = __half_as_ushort(__float2half(wy));
            u2 rec;
            rec.x = (ys << 16) | xs;
            rec.y = ((unsigned int)hy << 16) | hx;
            sp[tid] = rec;
        }
        __syncthreads();
        // ---- phase 1b: LDS-staged vectorized NT stores of vw / c3 ----
        // t0 is a multiple of 8 within the batch => float indices 16B-aligned.
        int vwbase = b * N + t0;
        if (tid < 64) {
            int j = tid * 4;
            if (j + 3 < cnt) {
                f4 v = {svw[j], svw[j + 1], svw[j + 2], svw[j + 3]};
                __builtin_nontemporal_store(v, (f4*)&out_vw[vwbase + j]);
            } else {
                for (int l = 0; l < 4; l++)
                    if (j + l < cnt) out_vw[vwbase + j + l] = svw[j + l];
            }
        } else if (tid < 256) {
            int j = (tid - 64) * 4;          // float offset into this tile's c3 block
            int tot = cnt * 3;
            if (j + 3 < tot) {
                f4 v = {sc3f[j], sc3f[j + 1], sc3f[j + 2], sc3f[j + 3]};
                __builtin_nontemporal_store(v, (f4*)&out_c3[(size_t)vwbase * 3 + j]);
            } else {
                for (int l = 0; l < 4; l++)
                    if (j + l < tot) out_c3[(size_t)vwbase * 3 + j + l] = sc3f[j + l];
            }
        }
        // ---- phase 2: gather, 8 slots x 32 lanes ----
        for (int i = slot; i < cnt; i += 8) {
            u2 rec = sp[i];   // slot-uniform -> LDS broadcast
            int n = t0 + i;
            int x0 = (int)(rec.x & 0xffff) - 8;
            int y0 = (int)(rec.x >> 16) - 8;
            float wx = __half2float(__ushort_as_half((unsigned short)(rec.y & 0xffff)));
            float wy = __half2float(__ushort_as_half((unsigned short)(rec.y >> 16)));
            int xA = min(max(x0, 0), WF - 1), xB = min(max(x0 + 1, 0), WF - 1);
            int yA = min(max(y0, 0), HF - 1), yB = min(max(y0 + 1, 0), HF - 1);
            float okxA = (x0 >= 0 && x0 < WF) ? 1.0f : 0.0f;
            float okxB = (x0 + 1 >= 0 && x0 + 1 < WF) ? 1.0f : 0.0f;
            float okyA = (y0 >= 0 && y0 < HF) ? 1.0f : 0.0f;
            float okyB = (y0 + 1 >= 0 && y0 + 1 < HF) ? 1.0f : 0.0f;
            float w00 = (1.0f - wx) * (1.0f - wy) * okxA * okyA;
            float w10 = wx * (1.0f - wy) * okxB * okyA;
            float w01 = (1.0f - wx) * wy * okxA * okyB;
            float w11 = wx * wy * okxB * okyB;
            const u2* q00 = (const u2*)(base + ((size_t)yA * WF + xA) * CC + co);
            const u2* q10 = (const u2*)(base + ((size_t)yA * WF + xB) * CC + co);
            const u2* q01 = (const u2*)(base + ((size_t)yB * WF + xA) * CC + co);
            const u2* q11 = (const u2*)(base + ((size_t)yB * WF + xB) * CC + co);
            u2 r00 = *q00, r10 = *q10, r01 = *q01, r11 = *q11;
#define BF16X4(r, v)                                                \
            f4 v;                                                   \
            v.x = __uint_as_float((r.x & 0xffffu) << 16);           \
            v.y = __uint_as_float(r.x & 0xffff0000u);               \
            v.z = __uint_as_float((r.y & 0xffffu) << 16);           \
            v.w = __uint_as_float(r.y & 0xffff0000u);
            BF16X4(r00, v00); BF16X4(r10, v10); BF16X4(r01, v01); BF16X4(r11, v11);
#undef BF16X4
            f4 acc = v00 * w00 + v10 * w10 + v01 * w01 + v11 * w11;
            __builtin_nontemporal_store(acc, obase + (size_t)n * (CC / 4) + lane);
        }
        __syncthreads();
    }
}

extern "C" void kernel_launch(void* const* d_in, const int* in_sizes, int n_in,
                              void* d_out, int out_size, void* d_ws, size_t ws_size,
                              hipStream_t stream) {
    const float* fm = (const float*)d_in[0];
    const float* v2d = (const float*)d_in[1];
    const float* v3d = (const float*)d_in[2];
    const int* parents = (const int*)d_in[3];
    const float* bary = (const float*)d_in[4];
    const int* pH = (const int*)d_in[5];
    const int* pW = (const int*)d_in[6];

    int Nv = in_sizes[1] / (BB * 2);
    int N = in_sizes[3] / 3;
    int K = in_sizes[4] / 3;

    // workspace layout: fmT bf16 (16.8MB) | depth (4MB)
    unsigned short* fmT = (unsigned short*)d_ws;
    float* depth = (float*)(fmT + (size_t)BB * HF * WF * CC);

    float* out_lf = (float*)d_out;
    float* out_vw = out_lf + (size_t)BB * N * CC;
    float* out_c3 = out_vw + (size_t)BB * N;

    hipLaunchKernelGGL(transpose_fm, dim3(HF * WF / 32, CC / 32, BB), dim3(32, 8), 0, stream,
                       fm, fmT, depth);
    hipLaunchKernelGGL(depth_scatter, dim3((BB * Nv + 255) / 256), dim3(256), 0, stream,
                       v2d, v3d, depth, Nv, pH, pW);
    hipLaunchKernelGGL(gather_fused, dim3(GATHER_NB), dim3(256), 0, stream,
                       fmT, v2d, v3d, parents, bary, depth, out_vw, out_c3, out_lf,
                       N, Nv, K, pH, pW);
}

// Round 13
// 190.621 us; speedup vs baseline: 1.0404x; 1.0404x over previous
//
#include <hip/hip_runtime.h>
#include <hip/hip_fp16.h>
#include <math.h>

#define BB 4
#define CC 128
#define HF 128
#define WF 128
#define GATHER_NB 2048   // 8 groups x 256 blocks x 4 waves = 1024 wave-spans/group

typedef float f4 __attribute__((ext_vector_type(4)));
typedef unsigned int u2 __attribute__((ext_vector_type(2)));

// ---------- helpers with fp-contract OFF to bit-match the numpy reference ----------
__device__ __forceinline__ float wsum3(float a, float wa, float b, float wb, float c, float wc) {
#pragma clang fp contract(off)
    {
        float r = a * wa;
        r = r + b * wb;
        r = r + c * wc;
        return r;
    }
}

__device__ __forceinline__ float to_pix(float cv, int Wm1, int WFm1) {
#pragma clang fp contract(off)
    {
        float g = cv / (float)Wm1 * 2.0f - 1.0f;
        return (g + 1.0f) * 0.5f * (float)WFm1;
    }
}

__device__ __forceinline__ unsigned short f32_bf16_rne(float f) {
    unsigned int u = __float_as_uint(f);
    unsigned int r = u + 0x7fffu + ((u >> 16) & 1u);
    return (unsigned short)(r >> 16);
}

// ---------- 1. NCHW -> NHWC bf16 transpose of feature_map, fused with depth init ----------
__global__ void transpose_fm(const float* __restrict__ fm, unsigned short* __restrict__ fmT,
                             float* __restrict__ depth) {
    __shared__ float tile[32][33];
    int b = blockIdx.z;
    int hw0 = blockIdx.x * 32;
    int c0 = blockIdx.y * 32;
    int tx = threadIdx.x;
    int ty = threadIdx.y;
    int gid = (((blockIdx.z * gridDim.y + blockIdx.y) * gridDim.x + blockIdx.x) << 8) +
              (ty << 5) + tx;
    if (gid < BB * 512 * 512) depth[gid] = INFINITY;
    const float* in = fm + (size_t)b * CC * HF * WF;
    unsigned short* out = fmT + (size_t)b * HF * WF * CC;
    #pragma unroll
    for (int i = ty; i < 32; i += 8)
        tile[i][tx] = in[(size_t)(c0 + i) * (HF * WF) + hw0 + tx];
    __syncthreads();
    #pragma unroll
    for (int i = ty; i < 32; i += 8)
        out[(size_t)(hw0 + i) * CC + c0 + tx] = f32_bf16_rne(tile[tx][i]);
}

// ---------- 2. scatter-min of vertex depths ----------
__global__ void depth_scatter(const float* __restrict__ v2d, const float* __restrict__ v3d,
                              float* __restrict__ depth, int Nv, const int* pH, const int* pW) {
    int H = *pH, W = *pW;
    int i = blockIdx.x * blockDim.x + threadIdx.x;
    if (i >= BB * Nv) return;
    int b = i / Nv, v = i - b * Nv;
    float x = v2d[((size_t)b * Nv + v) * 2 + 0];
    float y = v2d[((size_t)b * Nv + v) * 2 + 1];
    int xv = (int)rintf(x);
    int yv = (int)rintf(y);
    if (xv < 0 || xv >= W || yv < 0 || yv >= H) return;
    float z = v3d[((size_t)b * Nv + v) * 3 + 2];
    atomicMin((int*)&depth[(size_t)b * H * W + (size_t)yv * W + xv], __float_as_int(z));
}

// ---------- 3. fused setup + gather; groups = (batch, point-half); wave-sync tiles ----
// Each WAVE owns a contiguous span of points and a private 64-entry LDS param
// region -> no __syncthreads at all. NT loads only on no-reuse streams
// (parents, depth); vertex tables stay cached (R12 lesson).
__global__ void __launch_bounds__(256)
gather_fused(const unsigned short* __restrict__ fmT,
             const float* __restrict__ v2d, const float* __restrict__ v3d,
             const int* __restrict__ parents, const float* __restrict__ bary,
             const float* __restrict__ depth,
             float* __restrict__ out_vw, float* __restrict__ out_c3,
             float* __restrict__ out, int N, int Nv, int K,
             const int* pH, const int* pW) {
    __shared__ u2 sp[256];
    int tid = threadIdx.x;
    int group = blockIdx.x & 7;       // -> XCD
    int off = blockIdx.x >> 3;        // 0..255 within group
    int wave = tid >> 6;              // 0..3
    int lane = tid & 63;
    int b = group >> 1;               // batch
    int p = group & 1;                // point half
    int half = (N + 1) >> 1;
    int gstart = p * half;
    int gend = min(gstart + half, N);
    int wvid = off * 4 + wave;        // 0..1023 within group
    int wspan = (gend - gstart + 1023) >> 10;
    int start = gstart + wvid * wspan;
    int end = min(start + wspan, gend);
    int H = *pH, W = *pW;
    int co = (lane & 31) * 4;         // 32 lanes x 4 ch = 128 channels
    int sub = lane >> 5;              // 2 points per gather iteration
    u2* wsp = &sp[wave * 64];
    const unsigned short* base = fmT + (size_t)b * HF * WF * CC;
    const float* v2b = v2d + (size_t)b * Nv * 2;
    const float* v3b = v3d + (size_t)b * Nv * 3;
    const float* dep = depth + (size_t)b * H * W;
    f4* obase = (f4*)out + (size_t)b * N * (CC / 4);

    for (int t0 = start; t0 < end; t0 += 64) {
        int cnt = min(end - t0, 64);
        // ---- phase 1: one point's setup per lane ----
        if (lane < cnt) {
            int n = t0 + lane;
            int idx = b * N + n;
            int k = n % K;
            float w0 = bary[k * 3 + 0], w1 = bary[k * 3 + 1], w2 = bary[k * 3 + 2];
            int i0 = __builtin_nontemporal_load(&parents[(size_t)n * 3 + 0]);
            int i1 = __builtin_nontemporal_load(&parents[(size_t)n * 3 + 1]);
            int i2 = __builtin_nontemporal_load(&parents[(size_t)n * 3 + 2]);
            float ax = v2b[(size_t)i0 * 2], ay = v2b[(size_t)i0 * 2 + 1];
            float bx = v2b[(size_t)i1 * 2], by = v2b[(size_t)i1 * 2 + 1];
            float cx = v2b[(size_t)i2 * 2], cy = v2b[(size_t)i2 * 2 + 1];
            float c2x = wsum3(ax, w0, bx, w1, cx, w2);
            float c2y = wsum3(ay, w0, by, w1, cy, w2);
            float a0 = v3b[(size_t)i0 * 3], a1 = v3b[(size_t)i0 * 3 + 1], a2 = v3b[(size_t)i0 * 3 + 2];
            float b0 = v3b[(size_t)i1 * 3], b1 = v3b[(size_t)i1 * 3 + 1], b2 = v3b[(size_t)i1 * 3 + 2];
            float c0 = v3b[(size_t)i2 * 3], c1 = v3b[(size_t)i2 * 3 + 1], c2 = v3b[(size_t)i2 * 3 + 2];
            float c3x = wsum3(a0, w0, b0, w1, c0, w2);
            float c3y = wsum3(a1, w0, b1, w1, c1, w2);
            float c3z = wsum3(a2, w0, b2, w1, c2, w2);
            float e1x = b0 - a0, e1y = b1 - a1, e1z = b2 - a2;
            float e2x = c0 - a0, e2y = c1 - a1, e2z = c2 - a2;
            float nx = e1y * e2z - e1z * e2y;
            float ny = e1z * e2x - e1x * e2z;
            float nz = e1x * e2y - e1y * e2x;
            float nn = sqrtf(nx * nx + ny * ny + nz * nz) + 1e-8f;
            nx /= nn; ny /= nn; nz /= nn;
            float vn = sqrtf(c3x * c3x + c3y * c3y + c3z * c3z) + 1e-8f;
            float vx = -c3x / vn, vy = -c3y / vn, vz = -c3z / vn;
            float ang = fmaxf(nx * vx + ny * vy + nz * vz, 0.0f);
            int xc = (int)rintf(c2x); xc = min(max(xc, 0), W - 1);
            int yc = (int)rintf(c2y); yc = min(max(yc, 0), H - 1);
            float dsamp = __builtin_nontemporal_load(&dep[(size_t)yc * W + xc]);
            bool visible = (c3z <= dsamp + 1e-3f) || isinf(dsamp);
            out_vw[idx] = visible ? ang : 0.0f;
            out_c3[(size_t)idx * 3 + 0] = c3x;
            out_c3[(size_t)idx * 3 + 1] = c3y;
            out_c3[(size_t)idx * 3 + 2] = c3z;
            float px = to_pix(c2x, W - 1, WF - 1);
            float py = to_pix(c2y, H - 1, HF - 1);
            float x0f = floorf(px), y0f = floorf(py);
            int x0i = (int)x0f, y0i = (int)y0f;
            float wx = px - x0f, wy = py - y0f;
            unsigned int xs = (unsigned int)min(max(x0i + 8, 0), 65535);
            unsigned int ys = (unsigned int)min(max(y0i + 8, 0), 65535);
            unsigned short hx = __half_as_ushort(__float2half(wx));
            unsigned short hy = __half_as_ushort(__float2half(wy));
            u2 rec;
            rec.x = (ys << 16) | xs;
            rec.y = ((unsigned int)hy << 16) | hx;
            wsp[lane] = rec;
        }
        __builtin_amdgcn_wave_barrier();   // no-op fence: keep phase order
        // ---- phase 2: gather, 2 points x 32 lanes per iteration ----
        for (int i = 0; i < cnt; i += 2) {
            int pi = i + sub;
            if (pi >= cnt) continue;
            u2 rec = wsp[pi];   // half-wave-uniform -> LDS broadcast
            int n = t0 + pi;
            int x0 = (int)(rec.x & 0xffff) - 8;
            int y0 = (int)(rec.x >> 16) - 8;
            float wx = __half2float(__ushort_as_half((unsigned short)(rec.y & 0xffff)));
            float wy = __half2float(__ushort_as_half((unsigned short)(rec.y >> 16)));
            int xA = min(max(x0, 0), WF - 1), xB = min(max(x0 + 1, 0), WF - 1);
            int yA = min(max(y0, 0), HF - 1), yB = min(max(y0 + 1, 0), HF - 1);
            float okxA = (x0 >= 0 && x0 < WF) ? 1.0f : 0.0f;
            float okxB = (x0 + 1 >= 0 && x0 + 1 < WF) ? 1.0f : 0.0f;
            float okyA = (y0 >= 0 && y0 < HF) ? 1.0f : 0.0f;
            float okyB = (y0 + 1 >= 0 && y0 + 1 < HF) ? 1.0f : 0.0f;
            float w00 = (1.0f - wx) * (1.0f - wy) * okxA * okyA;
            float w10 = wx * (1.0f - wy) * okxB * okyA;
            float w01 = (1.0f - wx) * wy * okxA * okyB;
            float w11 = wx * wy * okxB * okyB;
            const u2* q00 = (const u2*)(base + ((size_t)yA * WF + xA) * CC + co);
            const u2* q10 = (const u2*)(base + ((size_t)yA * WF + xB) * CC + co);
            const u2* q01 = (const u2*)(base + ((size_t)yB * WF + xA) * CC + co);
            const u2* q11 = (const u2*)(base + ((size_t)yB * WF + xB) * CC + co);
            u2 r00 = *q00, r10 = *q10, r01 = *q01, r11 = *q11;
#define BF16X4(r, v)                                                \
            f4 v;                                                   \
            v.x = __uint_as_float((r.x & 0xffffu) << 16);           \
            v.y = __uint_as_float(r.x & 0xffff0000u);               \
            v.z = __uint_as_float((r.y & 0xffffu) << 16);           \
            v.w = __uint_as_float(r.y & 0xffff0000u);
            BF16X4(r00, v00); BF16X4(r10, v10); BF16X4(r01, v01); BF16X4(r11, v11);
#undef BF16X4
            f4 acc = v00 * w00 + v10 * w10 + v01 * w01 + v11 * w11;
            __builtin_nontemporal_store(acc, obase + (size_t)n * (CC / 4) + (lane & 31));
        }
        __builtin_amdgcn_wave_barrier();   // keep next tile's sp writes behind reads
    }
}

extern "C" void kernel_launch(void* const* d_in, const int* in_sizes, int n_in,
                              void* d_out, int out_size, void* d_ws, size_t ws_size,
                              hipStream_t stream) {
    const float* fm = (const float*)d_in[0];
    const float* v2d = (const float*)d_in[1];
    const float* v3d = (const float*)d_in[2];
    const int* parents = (const int*)d_in[3];
    const float* bary = (const float*)d_in[4];
    const int* pH = (const int*)d_in[5];
    const int* pW = (const int*)d_in[6];

    int Nv = in_sizes[1] / (BB * 2);
    int N = in_sizes[3] / 3;
    int K = in_sizes[4] / 3;

    // workspace layout: fmT bf16 (16.8MB) | depth (4MB)
    unsigned short* fmT = (unsigned short*)d_ws;
    float* depth = (float*)(fmT + (size_t)BB * HF * WF * CC);

    float* out_lf = (float*)d_out;
    float* out_vw = out_lf + (size_t)BB * N * CC;
    float* out_c3 = out_vw + (size_t)BB * N;

    hipLaunchKernelGGL(transpose_fm, dim3(HF * WF / 32, CC / 32, BB), dim3(32, 8), 0, stream,
                       fm, fmT, depth);
    hipLaunchKernelGGL(depth_scatter, dim3((BB * Nv + 255) / 256), dim3(256), 0, stream,
                       v2d, v3d, depth, Nv, pH, pW);
    hipLaunchKernelGGL(gather_fused, dim3(GATHER_NB), dim3(256), 0, stream,
                       fmT, v2d, v3d, parents, bary, depth, out_vw, out_c3, out_lf,
                       N, Nv, K, pH, pW);
}

// Round 14
// 117.282 us; speedup vs baseline: 1.6909x; 1.6253x over previous
//
#include <hip/hip_runtime.h>
#include <hip/hip_fp16.h>
#include <math.h>

#define BB 4
#define CC 128
#define HF 128
#define WF 128
#define GATHER_NB 2048   // 8 groups x 256 blocks

typedef float f4 __attribute__((ext_vector_type(4)));
typedef unsigned int u2 __attribute__((ext_vector_type(2)));

// ---------- helpers with fp-contract OFF to bit-match the numpy reference ----------
__device__ __forceinline__ float wsum3(float a, float wa, float b, float wb, float c, float wc) {
#pragma clang fp contract(off)
    {
        float r = a * wa;
        r = r + b * wb;
        r = r + c * wc;
        return r;
    }
}

__device__ __forceinline__ float to_pix(float cv, int Wm1, int WFm1) {
#pragma clang fp contract(off)
    {
        float g = cv / (float)Wm1 * 2.0f - 1.0f;
        return (g + 1.0f) * 0.5f * (float)WFm1;
    }
}

__device__ __forceinline__ unsigned short f32_bf16_rne(float f) {
    unsigned int u = __float_as_uint(f);
    unsigned int r = u + 0x7fffu + ((u >> 16) & 1u);
    return (unsigned short)(r >> 16);
}

// ---------- 1. NCHW -> NHWC bf16 transpose of feature_map, fused with depth init ----------
__global__ void transpose_fm(const float* __restrict__ fm, unsigned short* __restrict__ fmT,
                             float* __restrict__ depth) {
    __shared__ float tile[32][33];
    int b = blockIdx.z;
    int hw0 = blockIdx.x * 32;
    int c0 = blockIdx.y * 32;
    int tx = threadIdx.x;
    int ty = threadIdx.y;
    int gid = (((blockIdx.z * gridDim.y + blockIdx.y) * gridDim.x + blockIdx.x) << 8) +
              (ty << 5) + tx;
    if (gid < BB * 512 * 512) depth[gid] = INFINITY;
    const float* in = fm + (size_t)b * CC * HF * WF;
    unsigned short* out = fmT + (size_t)b * HF * WF * CC;
    #pragma unroll
    for (int i = ty; i < 32; i += 8)
        tile[i][tx] = in[(size_t)(c0 + i) * (HF * WF) + hw0 + tx];
    __syncthreads();
    #pragma unroll
    for (int i = ty; i < 32; i += 8)
        out[(size_t)(hw0 + i) * CC + c0 + tx] = f32_bf16_rne(tile[tx][i]);
}

// ---------- 2. scatter-min of vertex depths ----------
__global__ void depth_scatter(const float* __restrict__ v2d, const float* __restrict__ v3d,
                              float* __restrict__ depth, int Nv, const int* pH, const int* pW) {
    int H = *pH, W = *pW;
    int i = blockIdx.x * blockDim.x + threadIdx.x;
    if (i >= BB * Nv) return;
    int b = i / Nv, v = i - b * Nv;
    float x = v2d[((size_t)b * Nv + v) * 2 + 0];
    float y = v2d[((size_t)b * Nv + v) * 2 + 1];
    int xv = (int)rintf(x);
    int yv = (int)rintf(y);
    if (xv < 0 || xv >= W || yv < 0 || yv >= H) return;
    float z = v3d[((size_t)b * Nv + v) * 3 + 2];
    atomicMin((int*)&depth[(size_t)b * H * W + (size_t)yv * W + xv], __float_as_int(z));
}

// ---------- 3. fused setup + gather; groups = (batch, point-half) ----------
// R11 structure (best: 114.5us). Single change: vw/c3 leave via LDS-staged
// vectorized f4 NT stores (no L2 write-allocate pollution, no partial lines).
// NO nontemporal loads anywhere (R12/R13 lesson: NT loads on reused data poison).
__global__ void __launch_bounds__(256)
gather_fused(const unsigned short* __restrict__ fmT,
             const float* __restrict__ v2d, const float* __restrict__ v3d,
             const int* __restrict__ parents, const float* __restrict__ bary,
             const float* __restrict__ depth,
             float* __restrict__ out_vw, float* __restrict__ out_c3,
             float* __restrict__ out, int N, int Nv, int K,
             const int* pH, const int* pW) {
    __shared__ u2 sp[256];
    __shared__ float svw[256];
    __shared__ float sc3f[768];
    int tid = threadIdx.x;
    int group = blockIdx.x & 7;       // -> XCD
    int off = blockIdx.x >> 3;        // 0..255 within group
    int b = group >> 1;               // batch
    int p = group & 1;                // point half
    int half = (N + 1) >> 1;
    int gstart = p * half;
    int gend = min(gstart + half, N);
    int span = (gend - gstart + 255) >> 8;   // points per block
    span = (span + 7) & ~7;                  // multiple of 8 -> t0 stays 8-aligned
    int start = gstart + off * span;
    int end = min(start + span, gend);
    int H = *pH, W = *pW;
    int lane = tid & 31;              // 32 lanes x 4 ch = 128 channels
    int slot = tid >> 5;              // 8 point-slots
    int co = lane * 4;
    const unsigned short* base = fmT + (size_t)b * HF * WF * CC;
    const float* v2b = v2d + (size_t)b * Nv * 2;
    const float* v3b = v3d + (size_t)b * Nv * 3;
    const float* dep = depth + (size_t)b * H * W;
    f4* obase = (f4*)out + (size_t)b * N * (CC / 4);

    for (int t0 = start; t0 < end; t0 += 256) {
        int cnt = min(end - t0, 256);
        // ---- phase 1: setup for up to 256 points ----
        if (tid < cnt) {
            int n = t0 + tid;
            int k = n % K;
            float w0 = bary[k * 3 + 0], w1 = bary[k * 3 + 1], w2 = bary[k * 3 + 2];
            int i0 = parents[(size_t)n * 3 + 0];
            int i1 = parents[(size_t)n * 3 + 1];
            int i2 = parents[(size_t)n * 3 + 2];
            float ax = v2b[(size_t)i0 * 2], ay = v2b[(size_t)i0 * 2 + 1];
            float bx = v2b[(size_t)i1 * 2], by = v2b[(size_t)i1 * 2 + 1];
            float cx = v2b[(size_t)i2 * 2], cy = v2b[(size_t)i2 * 2 + 1];
            float c2x = wsum3(ax, w0, bx, w1, cx, w2);
            float c2y = wsum3(ay, w0, by, w1, cy, w2);
            float a0 = v3b[(size_t)i0 * 3], a1 = v3b[(size_t)i0 * 3 + 1], a2 = v3b[(size_t)i0 * 3 + 2];
            float b0 = v3b[(size_t)i1 * 3], b1 = v3b[(size_t)i1 * 3 + 1], b2 = v3b[(size_t)i1 * 3 + 2];
            float c0 = v3b[(size_t)i2 * 3], c1 = v3b[(size_t)i2 * 3 + 1], c2 = v3b[(size_t)i2 * 3 + 2];
            float c3x = wsum3(a0, w0, b0, w1, c0, w2);
            float c3y = wsum3(a1, w0, b1, w1, c1, w2);
            float c3z = wsum3(a2, w0, b2, w1, c2, w2);
            float e1x = b0 - a0, e1y = b1 - a1, e1z = b2 - a2;
            float e2x = c0 - a0, e2y = c1 - a1, e2z = c2 - a2;
            float nx = e1y * e2z - e1z * e2y;
            float ny = e1z * e2x - e1x * e2z;
            float nz = e1x * e2y - e1y * e2x;
            float nn = sqrtf(nx * nx + ny * ny + nz * nz) + 1e-8f;
            nx /= nn; ny /= nn; nz /= nn;
            float vn = sqrtf(c3x * c3x + c3y * c3y + c3z * c3z) + 1e-8f;
            float vx = -c3x / vn, vy = -c3y / vn, vz = -c3z / vn;
            float ang = fmaxf(nx * vx + ny * vy + nz * vz, 0.0f);
            int xc = (int)rintf(c2x); xc = min(max(xc, 0), W - 1);
            int yc = (int)rintf(c2y); yc = min(max(yc, 0), H - 1);
            float dsamp = dep[(size_t)yc * W + xc];
            bool visible = (c3z <= dsamp + 1e-3f) || isinf(dsamp);
            svw[tid] = visible ? ang : 0.0f;
            sc3f[tid * 3 + 0] = c3x;
            sc3f[tid * 3 + 1] = c3y;
            sc3f[tid * 3 + 2] = c3z;
            float px = to_pix(c2x, W - 1, WF - 1);
            float py = to_pix(c2y, H - 1, HF - 1);
            float x0f = floorf(px), y0f = floorf(py);
            int x0i = (int)x0f, y0i = (int)y0f;
            float wx = px - x0f, wy = py - y0f;
            unsigned int xs = (unsigned int)min(max(x0i + 8, 0), 65535);
            unsigned int ys = (unsigned int)min(max(y0i + 8, 0), 65535);
            unsigned short hx = __half_as_ushort(__float2half(wx));
            unsigned short hy = __half_as_ushort(__float2half(wy));
            u2 rec;
            rec.x = (ys << 16) | xs;
            rec.y = ((unsigned int)hy << 16) | hx;
            sp[tid] = rec;
        }
        __syncthreads();
        // ---- phase 1b: LDS-staged vectorized NT stores of vw / c3 ----
        // t0 multiple of 8 and N,gstart multiples of 4 => 16B-aligned f4 stores.
        {
            int vwbase = b * N + t0;
            if (tid < 64) {
                int j = tid * 4;
                if (j + 3 < cnt) {
                    f4 v = {svw[j], svw[j + 1], svw[j + 2], svw[j + 3]};
                    __builtin_nontemporal_store(v, (f4*)&out_vw[vwbase + j]);
                } else {
                    for (int l = 0; l < 4; l++)
                        if (j + l < cnt) out_vw[vwbase + j + l] = svw[j + l];
                }
            } else {
                int j = (tid - 64) * 4;       // float offset into this tile's c3 block
                int tot = cnt * 3;
                if (j + 3 < tot) {
                    f4 v = {sc3f[j], sc3f[j + 1], sc3f[j + 2], sc3f[j + 3]};
                    __builtin_nontemporal_store(v, (f4*)&out_c3[(size_t)vwbase * 3 + j]);
                } else {
                    for (int l = 0; l < 4; l++)
                        if (j + l < tot) out_c3[(size_t)vwbase * 3 + j + l] = sc3f[j + l];
                }
            }
        }
        // ---- phase 2: gather 256 points, 8 slots x 32 lanes ----
        for (int i = slot; i < cnt; i += 8) {
            u2 rec = sp[i];   // slot-uniform -> LDS broadcast
            int n = t0 + i;
            int x0 = (int)(rec.x & 0xffff) - 8;
            int y0 = (int)(rec.x >> 16) - 8;
            float wx = __half2float(__ushort_as_half((unsigned short)(rec.y & 0xffff)));
            float wy = __half2float(__ushort_as_half((unsigned short)(rec.y >> 16)));
            int xA = min(max(x0, 0), WF - 1), xB = min(max(x0 + 1, 0), WF - 1);
            int yA = min(max(y0, 0), HF - 1), yB = min(max(y0 + 1, 0), HF - 1);
            float okxA = (x0 >= 0 && x0 < WF) ? 1.0f : 0.0f;
            float okxB = (x0 + 1 >= 0 && x0 + 1 < WF) ? 1.0f : 0.0f;
            float okyA = (y0 >= 0 && y0 < HF) ? 1.0f : 0.0f;
            float okyB = (y0 + 1 >= 0 && y0 + 1 < HF) ? 1.0f : 0.0f;
            float w00 = (1.0f - wx) * (1.0f - wy) * okxA * okyA;
            float w10 = wx * (1.0f - wy) * okxB * okyA;
            float w01 = (1.0f - wx) * wy * okxA * okyB;
            float w11 = wx * wy * okxB * okyB;
            const u2* q00 = (const u2*)(base + ((size_t)yA * WF + xA) * CC + co);
            const u2* q10 = (const u2*)(base + ((size_t)yA * WF + xB) * CC + co);
            const u2* q01 = (const u2*)(base + ((size_t)yB * WF + xA) * CC + co);
            const u2* q11 = (const u2*)(base + ((size_t)yB * WF + xB) * CC + co);
            u2 r00 = *q00, r10 = *q10, r01 = *q01, r11 = *q11;
#define BF16X4(r, v)                                                \
            f4 v;                                                   \
            v.x = __uint_as_float((r.x & 0xffffu) << 16);           \
            v.y = __uint_as_float(r.x & 0xffff0000u);               \
            v.z = __uint_as_float((r.y & 0xffffu) << 16);           \
            v.w = __uint_as_float(r.y & 0xffff0000u);
            BF16X4(r00, v00); BF16X4(r10, v10); BF16X4(r01, v01); BF16X4(r11, v11);
#undef BF16X4
            f4 acc = v00 * w00 + v10 * w10 + v01 * w01 + v11 * w11;
            __builtin_nontemporal_store(acc, obase + (size_t)n * (CC / 4) + lane);
        }
        __syncthreads();
    }
}

extern "C" void kernel_launch(void* const* d_in, const int* in_sizes, int n_in,
                              void* d_out, int out_size, void* d_ws, size_t ws_size,
                              hipStream_t stream) {
    const float* fm = (const float*)d_in[0];
    const float* v2d = (const float*)d_in[1];
    const float* v3d = (const float*)d_in[2];
    const int* parents = (const int*)d_in[3];
    const float* bary = (const float*)d_in[4];
    const int* pH = (const int*)d_in[5];
    const int* pW = (const int*)d_in[6];

    int Nv = in_sizes[1] / (BB * 2);
    int N = in_sizes[3] / 3;
    int K = in_sizes[4] / 3;

    // workspace layout: fmT bf16 (16.8MB) | depth (4MB)
    unsigned short* fmT = (unsigned short*)d_ws;
    float* depth = (float*)(fmT + (size_t)BB * HF * WF * CC);

    float* out_lf = (float*)d_out;
    float* out_vw = out_lf + (size_t)BB * N * CC;
    float* out_c3 = out_vw + (size_t)BB * N;

    hipLaunchKernelGGL(transpose_fm, dim3(HF * WF / 32, CC / 32, BB), dim3(32, 8), 0, stream,
                       fm, fmT, depth);
    hipLaunchKernelGGL(depth_scatter, dim3((BB * Nv + 255) / 256), dim3(256), 0, stream,
                       v2d, v3d, depth, Nv, pH, pW);
    hipLaunchKernelGGL(gather_fused, dim3(GATHER_NB), dim3(256), 0, stream,
                       fmT, v2d, v3d, parents, bary, depth, out_vw, out_c3, out_lf,
                       N, Nv, K, pH, pW);
}